// Round 1
// baseline (399.364 us; speedup 1.0000x reference)
//
#include <hip/hip_runtime.h>

// Problem constants
#define B_N    64
#define S_LEN  1024
#define EMB    300
#define EMB_P  304              // padded token stride (halves) -> 608B, 16B-aligned
#define NGRAM  5
#define WPAD   1024             // windows per batch padded 1020 -> 1024
#define MTOT   (B_N * WPAD)     // 65536 rows
#define K1P    1536             // padded K for layer 1 (5*304 = 1520 -> 1536)
#define H0     512
#define H1D    256
#define H2D    128

typedef _Float16 half8 __attribute__((ext_vector_type(8)));
typedef float  floatx4 __attribute__((ext_vector_type(4)));

typedef const __attribute__((address_space(1))) void* gptr_t;
typedef __attribute__((address_space(3))) void* sptr_t;

__device__ __forceinline__ void gload16(const void* g, void* s) {
  __builtin_amdgcn_global_load_lds((gptr_t)g, (sptr_t)s, 16, 0, 0);
}

// ---------------------------------------------------------------- zero out
__global__ void zero_out_kernel(float* __restrict__ out) {
  int t = blockIdx.x * 256 + threadIdx.x;
  if (t < B_N * H2D) out[t] = 0.0f;
}

// ------------------------------------------------- gather table[x] -> fp16
// one thread per float4 chunk; chunk 75 zero-fills the 300..303 pad
__global__ void gather_kernel(const int* __restrict__ x,
                              const float* __restrict__ table,
                              _Float16* __restrict__ emb) {
  const int CH = EMB_P / 4;  // 76
  int tid = blockIdx.x * 256 + threadIdx.x;
  int tok = tid / CH;
  int c   = tid - tok * CH;
  int e   = c << 2;
  _Float16 h0, h1, h2, h3;
  if (e < EMB) {
    float4 v = *(const float4*)(table + (size_t)x[tok] * EMB + e);
    h0 = (_Float16)v.x; h1 = (_Float16)v.y; h2 = (_Float16)v.z; h3 = (_Float16)v.w;
  } else {
    h0 = h1 = h2 = h3 = (_Float16)0.0f;
  }
  union { float2 f2; _Float16 h[4]; } u;
  u.h[0] = h0; u.h[1] = h1; u.h[2] = h2; u.h[3] = h3;
  *(float2*)(emb + (size_t)tok * EMB_P + e) = u.f2;
}

// ----------------------------------- weights -> K-major (transposed) fp16
// WsT[n][k] over padded K'=1536: k -> (tn = k/304, e = k%304), zero in pads
__global__ void wprep_kernel(const float* __restrict__ Ws,
                             const float* __restrict__ W1,
                             const float* __restrict__ W2,
                             _Float16* __restrict__ WsT,
                             _Float16* __restrict__ W1T,
                             _Float16* __restrict__ W2T) {
  int tid = blockIdx.x * 256 + threadIdx.x;
  const int NS = H0 * K1P;            // 786432
  const int N1 = H1D * H0;            // 131072
  const int N2 = H2D * H1D;           // 32768
  if (tid < NS) {
    int n = tid / K1P, k = tid - n * K1P;
    float v = 0.0f;
    if (k < NGRAM * EMB_P) {
      int tn = k / EMB_P, e = k - tn * EMB_P;
      if (e < EMB) v = Ws[(size_t)(tn * EMB + e) * H0 + n];
    }
    WsT[tid] = (_Float16)v;
  } else if (tid < NS + N1) {
    int t = tid - NS;
    int n = t / H0, k = t - n * H0;
    W1T[t] = (_Float16)W1[(size_t)k * H1D + n];
  } else if (tid < NS + N1 + N2) {
    int t = tid - (NS + N1);
    int n = t / H1D, k = t - n * H1D;
    W2T[t] = (_Float16)W2[(size_t)k * H2D + n];
  }
}

// ------------------------------------------------------------ NT MFMA GEMM
// C[M,N] = A[M,K] @ Bt[N,K]^T, 128x128 tile, BK=32, 4 waves (2x2), fp16 MFMA.
// EPI 0: +bias, store fp16.  EPI 1: +bias, relu, store fp16.
// EPI 2: +bias, relu, masked-mean pooling via atomics (N=128, one tile).
template <int EPI>
__global__ __launch_bounds__(256, 2)
void gemm_nt(const _Float16* __restrict__ A, const _Float16* __restrict__ Bt,
             const float* __restrict__ bias, _Float16* __restrict__ C,
             float* __restrict__ out, const int* __restrict__ lengths,
             int N, int K, int lda, int nTiles) {
  __shared__ _Float16 sA[128 * 32];
  __shared__ _Float16 sB[128 * 32];
  __shared__ float red[2][128];

  const int tid  = threadIdx.x;
  const int wave = tid >> 6;
  const int lane = tid & 63;
  const int wr   = wave >> 1, wc = wave & 1;
  const int quad = lane >> 4, l16 = lane & 15;
  const int mt = blockIdx.x / nTiles;
  const int nt = blockIdx.x - mt * nTiles;
  const long mBase = (long)mt << 7;
  const int  nBase = nt << 7;

  // staging: wave-uniform LDS base + lane*16B (global_load_lds requirement)
  const int sRow = (wave << 4) + (lane >> 2);   // 0..63
  const int sCol = (lane & 3) << 3;             // halves: 0,8,16,24

  const _Float16* aG0 = A + (mBase + sRow) * lda + sCol;
  const _Float16* aG1 = A + (mBase + sRow + 64) * lda + sCol;
  const _Float16* bG0 = Bt + (long)(nBase + sRow) * K + sCol;
  const _Float16* bG1 = Bt + (long)(nBase + sRow + 64) * K + sCol;
  _Float16* sA0 = sA + sRow * 32 + sCol;
  _Float16* sA1 = sA0 + 64 * 32;
  _Float16* sB0 = sB + sRow * 32 + sCol;
  _Float16* sB1 = sB0 + 64 * 32;

  floatx4 acc[4][4] = {};

  for (int k0 = 0; k0 < K; k0 += 32) {
    gload16(aG0 + k0, sA0);
    gload16(aG1 + k0, sA1);
    gload16(bG0 + k0, sB0);
    gload16(bG1 + k0, sB1);
    __syncthreads();  // vmcnt(0) drain + barrier: LDS tiles ready
    half8 aF[4], bF[4];
#pragma unroll
    for (int i = 0; i < 4; i++)
      aF[i] = *(const half8*)(sA + ((wr << 6) + (i << 4) + l16) * 32 + (quad << 3));
#pragma unroll
    for (int j = 0; j < 4; j++)
      bF[j] = *(const half8*)(sB + ((wc << 6) + (j << 4) + l16) * 32 + (quad << 3));
#pragma unroll
    for (int i = 0; i < 4; i++)
#pragma unroll
      for (int j = 0; j < 4; j++)
        acc[i][j] = __builtin_amdgcn_mfma_f32_16x16x32_f16(aF[i], bF[j], acc[i][j], 0, 0, 0);
    __syncthreads();  // protect LDS before next stage's overwrite
  }

  if constexpr (EPI < 2) {
#pragma unroll
    for (int j = 0; j < 4; j++) {
      int col = nBase + (wc << 6) + (j << 4) + l16;
      float bv = bias[col];
#pragma unroll
      for (int i = 0; i < 4; i++) {
        long row = mBase + (wr << 6) + (i << 4) + (quad << 2);
#pragma unroll
        for (int r = 0; r < 4; r++) {
          float v = acc[i][j][r] + bv;
          if (EPI == 1) v = fmaxf(v, 0.0f);
          C[(size_t)(row + r) * N + col] = (_Float16)v;
        }
      }
    }
  } else {
    // fused relu + ragged-mean pooling. 1024 rows/batch = 8 tiles: whole
    // block is one batch. C/D layout: col = lane&15, row = quad*4 + reg.
    int b = mt >> 3;
    int validw = lengths[b] - (NGRAM - 1);
    float inv = 1.0f / (float)validw;
    int wBase = ((mt & 7) << 7) + (wr << 6);
#pragma unroll
    for (int j = 0; j < 4; j++) {
      int col = (wc << 6) + (j << 4) + l16;
      float bv = bias[col];
      float p = 0.0f;
#pragma unroll
      for (int i = 0; i < 4; i++) {
#pragma unroll
        for (int r = 0; r < 4; r++) {
          int w = wBase + (i << 4) + (quad << 2) + r;
          float v = fmaxf(acc[i][j][r] + bv, 0.0f);
          p += (w < validw) ? v : 0.0f;
        }
      }
      p *= inv;
      p += __shfl_xor(p, 16, 64);
      p += __shfl_xor(p, 32, 64);
      if (quad == 0) red[wr][col] = p;
    }
    __syncthreads();
    if (tid < 128) atomicAdd(out + b * H2D + tid, red[0][tid] + red[1][tid]);
  }
}

// ---------------------------------------------------------------- launcher
extern "C" void kernel_launch(void* const* d_in, const int* in_sizes, int n_in,
                              void* d_out, int out_size, void* d_ws, size_t ws_size,
                              hipStream_t stream) {
  const int*   x       = (const int*)d_in[0];
  const int*   lengths = (const int*)d_in[1];
  const float* table   = (const float*)d_in[2];
  const float* W_slide = (const float*)d_in[3];
  const float* b_slide = (const float*)d_in[4];
  const float* W1      = (const float*)d_in[5];
  const float* b1      = (const float*)d_in[6];
  const float* W2      = (const float*)d_in[7];
  const float* b2      = (const float*)d_in[8];
  float* out = (float*)d_out;

  // workspace layout (halves). emb gets +4096 pad: padded windows read past
  // the logical end (finite poison * nonzero weights, rows masked in pooling).
  _Float16* ws  = (_Float16*)d_ws;
  _Float16* emb = ws;                                   // 64*1024*304 = 19,922,944
  _Float16* WsT = emb + (size_t)MTOT * EMB_P + 4096;    // 512*1536
  _Float16* W1T = WsT + (size_t)H0 * K1P;               // 256*512
  _Float16* W2T = W1T + (size_t)H1D * H0;               // 128*256
  _Float16* h1  = W2T + (size_t)H2D * H1D;              // 65536*512
  _Float16* h2  = h1 + (size_t)MTOT * H0;               // 65536*256

  zero_out_kernel<<<32, 256, 0, stream>>>(out);
  gather_kernel<<<(MTOT * (EMB_P / 4)) / 256, 256, 0, stream>>>(x, table, emb);
  {
    int total = H0 * K1P + H1D * H0 + H2D * H1D;
    wprep_kernel<<<(total + 255) / 256, 256, 0, stream>>>(W_slide, W1, W2, WsT, W1T, W2T);
  }
  // L1: win @ W_slide + b_slide (no relu) -> h1 fp16
  gemm_nt<0><<<(MTOT / 128) * (H0 / 128), 256, 0, stream>>>(
      emb, WsT, b_slide, h1, nullptr, nullptr, H0, K1P, EMB_P, H0 / 128);
  // L2: relu(h1 @ W1 + b1) -> h2 fp16
  gemm_nt<1><<<(MTOT / 128) * (H1D / 128), 256, 0, stream>>>(
      h1, W1T, b1, h2, nullptr, nullptr, H1D, H0, H0, H1D / 128);
  // L3: relu(h2 @ W2 + b2), fused masked-mean pooling -> out
  gemm_nt<2><<<(MTOT / 128) * (H2D / 128), 256, 0, stream>>>(
      h2, W2T, b2, nullptr, out, lengths, H2D, H1D, H1D, H2D / 128);
}

// Round 2
// 393.128 us; speedup vs baseline: 1.0159x; 1.0159x over previous
//
#include <hip/hip_runtime.h>

// Problem constants
#define B_N    64
#define S_LEN  1024
#define EMB    300
#define EMB_P  304              // padded token stride (halves) -> 608B, 16B-aligned
#define NGRAM  5
#define WPAD   1024             // windows per batch padded 1020 -> 1024
#define MTOT   (B_N * WPAD)     // 65536 rows
#define K1P    1536             // padded K for layer 1 (5*304 = 1520 -> 1536)
#define H0     512
#define H1D    256
#define H2D    128

typedef _Float16 half8 __attribute__((ext_vector_type(8)));
typedef float  floatx4 __attribute__((ext_vector_type(4)));

typedef const __attribute__((address_space(1))) void* gptr_t;
typedef __attribute__((address_space(3))) void* sptr_t;

__device__ __forceinline__ void gload16(const void* g, void* s) {
  __builtin_amdgcn_global_load_lds((gptr_t)g, (sptr_t)s, 16, 0, 0);
}

// ---------------------------------------------------------------- zero out
__global__ void zero_out_kernel(float* __restrict__ out) {
  int t = blockIdx.x * 256 + threadIdx.x;
  if (t < B_N * H2D) out[t] = 0.0f;
}

// ------------------------------------------------- gather table[x] -> fp16
__global__ void gather_kernel(const int* __restrict__ x,
                              const float* __restrict__ table,
                              _Float16* __restrict__ emb) {
  const int CH = EMB_P / 4;  // 76
  int tid = blockIdx.x * 256 + threadIdx.x;
  int tok = tid / CH;
  int c   = tid - tok * CH;
  int e   = c << 2;
  _Float16 h0, h1, h2, h3;
  if (e < EMB) {
    float4 v = *(const float4*)(table + (size_t)x[tok] * EMB + e);
    h0 = (_Float16)v.x; h1 = (_Float16)v.y; h2 = (_Float16)v.z; h3 = (_Float16)v.w;
  } else {
    h0 = h1 = h2 = h3 = (_Float16)0.0f;
  }
  union { float2 f2; _Float16 h[4]; } u;
  u.h[0] = h0; u.h[1] = h1; u.h[2] = h2; u.h[3] = h3;
  *(float2*)(emb + (size_t)tok * EMB_P + e) = u.f2;
}

// ----------------------------------- weights -> K-major (transposed) fp16
__global__ void wprep_kernel(const float* __restrict__ Ws,
                             const float* __restrict__ W1,
                             const float* __restrict__ W2,
                             _Float16* __restrict__ WsT,
                             _Float16* __restrict__ W1T,
                             _Float16* __restrict__ W2T) {
  int tid = blockIdx.x * 256 + threadIdx.x;
  const int NS = H0 * K1P;            // 786432
  const int N1 = H1D * H0;            // 131072
  const int N2 = H2D * H1D;           // 32768
  if (tid < NS) {
    int n = tid / K1P, k = tid - n * K1P;
    float v = 0.0f;
    if (k < NGRAM * EMB_P) {
      int tn = k / EMB_P, e = k - tn * EMB_P;
      if (e < EMB) v = Ws[(size_t)(tn * EMB + e) * H0 + n];
    }
    WsT[tid] = (_Float16)v;
  } else if (tid < NS + N1) {
    int t = tid - NS;
    int n = t / H0, k = t - n * H0;
    W1T[t] = (_Float16)W1[(size_t)k * H1D + n];
  } else if (tid < NS + N1 + N2) {
    int t = tid - (NS + N1);
    int n = t / H1D, k = t - n * H1D;
    W2T[t] = (_Float16)W2[(size_t)k * H2D + n];
  }
}

// ------------------------------------------------------------ NT MFMA GEMM
// C[M,N] = A[M,K] @ Bt[N,K]^T, 128x128 tile, BK=32, 4 waves (2x2), fp16 MFMA.
// Double-buffered LDS (1 barrier/k-step) + XOR-swizzled 16B chunks:
//   chunk c of row r stored at slot c ^ ((r>>1)&3)  -> 2-way max bank alias.
// EPI 0: +bias, store fp16.  EPI 1: +bias, relu, store fp16.
// EPI 2: +bias, relu, masked-mean pooling via atomics (N=128, one tile).
template <int EPI>
__global__ __launch_bounds__(256, 2)
void gemm_nt(const _Float16* __restrict__ A, const _Float16* __restrict__ Bt,
             const float* __restrict__ bias, _Float16* __restrict__ C,
             float* __restrict__ out, const int* __restrict__ lengths,
             int N, int K, int lda, int nTiles) {
  __shared__ _Float16 sA[2][128 * 32];
  __shared__ _Float16 sB[2][128 * 32];
  __shared__ float red[2][128];

  const int tid  = threadIdx.x;
  const int wave = tid >> 6;
  const int lane = tid & 63;
  const int wr   = wave >> 1, wc = wave & 1;
  const int quad = lane >> 4, l16 = lane & 15;
  const int mt = blockIdx.x / nTiles;
  const int nt = blockIdx.x - mt * nTiles;
  const long mBase = (long)mt << 7;
  const int  nBase = nt << 7;

  // staging: LDS dest is wave-uniform base + lane*16B. Lane (row=sRow,
  // slot=lane&3) fetches global chunk gChunk so storage is XOR-swizzled.
  const int sRow   = (wave << 4) + (lane >> 2);        // 0..63
  const int sCol   = (lane & 3) << 3;                  // LDS slot (halves)
  const int gCol   = ((lane & 3) ^ ((sRow >> 1) & 3)) << 3;  // global chunk

  const _Float16* aG0 = A + (mBase + sRow) * lda + gCol;
  const _Float16* aG1 = A + (mBase + sRow + 64) * lda + gCol;   // (+64)>>1 &3 == same swz
  const _Float16* bG0 = Bt + (long)(nBase + sRow) * K + gCol;
  const _Float16* bG1 = Bt + (long)(nBase + sRow + 64) * K + gCol;
  const int offS0 = sRow * 32 + sCol;
  const int offS1 = offS0 + 64 * 32;

  // fragment-read swizzle: row = (wr<<6)+(i<<4)+l16 -> swz = (l16>>1)&3
  const int fswz = ((l16 >> 1) & 3) << 3;

  floatx4 acc[4][4] = {};

  const int nK = K >> 5;
  // prologue: stage k=0 into buf 0
  gload16(aG0, &sA[0][offS0]);
  gload16(aG1, &sA[0][offS1]);
  gload16(bG0, &sB[0][offS0]);
  gload16(bG1, &sB[0][offS1]);

  for (int kk = 0; kk < nK; kk++) {
    const int cur = kk & 1;
    __syncthreads();  // drains vmcnt(0): buf[cur] ready; orders vs prev reads of buf[cur^1]
    if (kk + 1 < nK) {
      const int ko = (kk + 1) << 5;
      gload16(aG0 + ko, &sA[cur ^ 1][offS0]);
      gload16(aG1 + ko, &sA[cur ^ 1][offS1]);
      gload16(bG0 + ko, &sB[cur ^ 1][offS0]);
      gload16(bG1 + ko, &sB[cur ^ 1][offS1]);
    }
    half8 aF[4], bF[4];
#pragma unroll
    for (int i = 0; i < 4; i++)
      aF[i] = *(const half8*)(&sA[cur][((wr << 6) + (i << 4) + l16) * 32 + ((quad << 3) ^ fswz)]);
#pragma unroll
    for (int j = 0; j < 4; j++)
      bF[j] = *(const half8*)(&sB[cur][((wc << 6) + (j << 4) + l16) * 32 + ((quad << 3) ^ fswz)]);
#pragma unroll
    for (int i = 0; i < 4; i++)
#pragma unroll
      for (int j = 0; j < 4; j++)
        acc[i][j] = __builtin_amdgcn_mfma_f32_16x16x32_f16(aF[i], bF[j], acc[i][j], 0, 0, 0);
  }

  if constexpr (EPI < 2) {
#pragma unroll
    for (int j = 0; j < 4; j++) {
      int col = nBase + (wc << 6) + (j << 4) + l16;
      float bv = bias[col];
#pragma unroll
      for (int i = 0; i < 4; i++) {
        long row = mBase + (wr << 6) + (i << 4) + (quad << 2);
#pragma unroll
        for (int r = 0; r < 4; r++) {
          float v = acc[i][j][r] + bv;
          if (EPI == 1) v = fmaxf(v, 0.0f);
          C[(size_t)(row + r) * N + col] = (_Float16)v;
        }
      }
    }
  } else {
    // fused relu + ragged-mean pooling. 1024 rows/batch = 8 tiles: whole
    // block is one batch. C/D layout: col = lane&15, row = quad*4 + reg.
    int b = mt >> 3;
    int validw = lengths[b] - (NGRAM - 1);
    float inv = 1.0f / (float)validw;
    int wBase = ((mt & 7) << 7) + (wr << 6);
#pragma unroll
    for (int j = 0; j < 4; j++) {
      int col = (wc << 6) + (j << 4) + l16;
      float bv = bias[col];
      float p = 0.0f;
#pragma unroll
      for (int i = 0; i < 4; i++) {
#pragma unroll
        for (int r = 0; r < 4; r++) {
          int w = wBase + (i << 4) + (quad << 2) + r;
          float v = fmaxf(acc[i][j][r] + bv, 0.0f);
          p += (w < validw) ? v : 0.0f;
        }
      }
      p *= inv;
      p += __shfl_xor(p, 16, 64);
      p += __shfl_xor(p, 32, 64);
      if (quad == 0) red[wr][col] = p;
    }
    __syncthreads();
    if (tid < 128) atomicAdd(out + b * H2D + tid, red[0][tid] + red[1][tid]);
  }
}

// ---------------------------------------------------------------- launcher
extern "C" void kernel_launch(void* const* d_in, const int* in_sizes, int n_in,
                              void* d_out, int out_size, void* d_ws, size_t ws_size,
                              hipStream_t stream) {
  const int*   x       = (const int*)d_in[0];
  const int*   lengths = (const int*)d_in[1];
  const float* table   = (const float*)d_in[2];
  const float* W_slide = (const float*)d_in[3];
  const float* b_slide = (const float*)d_in[4];
  const float* W1      = (const float*)d_in[5];
  const float* b1      = (const float*)d_in[6];
  const float* W2      = (const float*)d_in[7];
  const float* b2      = (const float*)d_in[8];
  float* out = (float*)d_out;

  // workspace layout (halves). emb gets +4096 pad: padded windows read past
  // the logical end (finite poison * zero pad-weights, rows masked in pooling).
  _Float16* ws  = (_Float16*)d_ws;
  _Float16* emb = ws;                                   // 64*1024*304
  _Float16* WsT = emb + (size_t)MTOT * EMB_P + 4096;    // 512*1536
  _Float16* W1T = WsT + (size_t)H0 * K1P;               // 256*512
  _Float16* W2T = W1T + (size_t)H1D * H0;               // 128*256
  _Float16* h1  = W2T + (size_t)H2D * H1D;              // 65536*512
  _Float16* h2  = h1 + (size_t)MTOT * H0;               // 65536*256

  zero_out_kernel<<<32, 256, 0, stream>>>(out);
  gather_kernel<<<(MTOT * (EMB_P / 4)) / 256, 256, 0, stream>>>(x, table, emb);
  {
    int total = H0 * K1P + H1D * H0 + H2D * H1D;
    wprep_kernel<<<(total + 255) / 256, 256, 0, stream>>>(W_slide, W1, W2, WsT, W1T, W2T);
  }
  // L1: win @ W_slide + b_slide (no relu) -> h1 fp16
  gemm_nt<0><<<(MTOT / 128) * (H0 / 128), 256, 0, stream>>>(
      emb, WsT, b_slide, h1, nullptr, nullptr, H0, K1P, EMB_P, H0 / 128);
  // L2: relu(h1 @ W1 + b1) -> h2 fp16
  gemm_nt<1><<<(MTOT / 128) * (H1D / 128), 256, 0, stream>>>(
      h1, W1T, b1, h2, nullptr, nullptr, H1D, H0, H0, H1D / 128);
  // L3: relu(h2 @ W2 + b2), fused masked-mean pooling -> out
  gemm_nt<2><<<(MTOT / 128) * (H2D / 128), 256, 0, stream>>>(
      h2, W2T, b2, nullptr, out, lengths, H2D, H1D, H1D, H2D / 128);
}

// Round 3
// 365.960 us; speedup vs baseline: 1.0913x; 1.0742x over previous
//
#include <hip/hip_runtime.h>

// Problem constants
#define B_N    64
#define S_LEN  1024
#define EMB    300
#define EMB_P  304              // padded token stride (halves) -> 608B, 16B-aligned
#define NGRAM  5
#define WPAD   1024             // windows per batch padded 1020 -> 1024
#define MTOT   (B_N * WPAD)     // 65536 rows
#define K1P    1536             // padded K for layer 1 (5*304 = 1520 -> 1536)
#define H0     512
#define H1D    256
#define H2D    128

typedef _Float16 half8 __attribute__((ext_vector_type(8)));
typedef float  floatx4 __attribute__((ext_vector_type(4)));

typedef const __attribute__((address_space(1))) void* gptr_t;
typedef __attribute__((address_space(3))) void* sptr_t;

__device__ __forceinline__ void gload16(const void* g, void* s) {
  __builtin_amdgcn_global_load_lds((gptr_t)g, (sptr_t)s, 16, 0, 0);
}

// ------------------------------- gather table[x] -> fp16 (+ zero d_out)
__global__ void gather_kernel(const int* __restrict__ x,
                              const float* __restrict__ table,
                              _Float16* __restrict__ emb,
                              float* __restrict__ out) {
  if (blockIdx.x < 32) out[blockIdx.x * 256 + threadIdx.x] = 0.0f;  // 8192 floats
  const int CH = EMB_P / 4;  // 76
  int tid = blockIdx.x * 256 + threadIdx.x;
  int tok = tid / CH;
  int c   = tid - tok * CH;
  int e   = c << 2;
  _Float16 h0, h1, h2, h3;
  if (e < EMB) {
    float4 v = *(const float4*)(table + (size_t)x[tok] * EMB + e);
    h0 = (_Float16)v.x; h1 = (_Float16)v.y; h2 = (_Float16)v.z; h3 = (_Float16)v.w;
  } else {
    h0 = h1 = h2 = h3 = (_Float16)0.0f;
  }
  union { float2 f2; _Float16 h[4]; } u;
  u.h[0] = h0; u.h[1] = h1; u.h[2] = h2; u.h[3] = h3;
  *(float2*)(emb + (size_t)tok * EMB_P + e) = u.f2;
}

// ----------------------------------- weights -> K-major (transposed) fp16
__global__ void wprep_kernel(const float* __restrict__ Ws,
                             const float* __restrict__ W1,
                             const float* __restrict__ W2,
                             _Float16* __restrict__ WsT,
                             _Float16* __restrict__ W1T,
                             _Float16* __restrict__ W2T) {
  int tid = blockIdx.x * 256 + threadIdx.x;
  const int NS = H0 * K1P;            // 786432
  const int N1 = H1D * H0;            // 131072
  const int N2 = H2D * H1D;           // 32768
  if (tid < NS) {
    int n = tid / K1P, k = tid - n * K1P;
    float v = 0.0f;
    if (k < NGRAM * EMB_P) {
      int tn = k / EMB_P, e = k - tn * EMB_P;
      if (e < EMB) v = Ws[(size_t)(tn * EMB + e) * H0 + n];
    }
    WsT[tid] = (_Float16)v;
  } else if (tid < NS + N1) {
    int t = tid - NS;
    int n = t / H0, k = t - n * H0;
    W1T[t] = (_Float16)W1[(size_t)k * H1D + n];
  } else if (tid < NS + N1 + N2) {
    int t = tid - (NS + N1);
    int n = t / H1D, k = t - n * H1D;
    W2T[t] = (_Float16)W2[(size_t)k * H2D + n];
  }
}

// ------------------------------------------------------------ NT MFMA GEMM
// C[M,N] = A[M,K] @ Bt[N,K]^T, 128x128 tile, BK=32, 4 waves (2x2), fp16 MFMA.
// Double-buffered LDS (1 barrier/k-step), XOR-swizzled 16B chunks (0 bank
// conflicts), 4 blocks/CU for latency hiding, XCD-affine block swizzle so
// N-tile siblings sharing an A-tile run back-to-back on the same XCD's L2.
// EPI 0: +bias, store fp16.  EPI 1: +bias, relu, store fp16.
// EPI 2: +bias, relu, masked-mean pooling via atomics (N=128, one tile).
template <int EPI>
__global__ __launch_bounds__(256, 4)
void gemm_nt(const _Float16* __restrict__ A, const _Float16* __restrict__ Bt,
             const float* __restrict__ bias, _Float16* __restrict__ C,
             float* __restrict__ out, const int* __restrict__ lengths,
             int N, int K, int lda, int nTiles) {
  __shared__ _Float16 sA[2][128 * 32];
  __shared__ _Float16 sB[2][128 * 32];
  __shared__ float red[2][128];

  const int tid  = threadIdx.x;
  const int wave = tid >> 6;
  const int lane = tid & 63;
  const int wr   = wave >> 1, wc = wave & 1;
  const int quad = lane >> 4, l16 = lane & 15;

  // XCD-affine remap: physical p -> xcd = p&7 gets contiguous logical range;
  // nt varies fastest within a range -> A-tile L2 reuse within one XCD.
  const int perX = gridDim.x >> 3;
  const int L    = (blockIdx.x & 7) * perX + (blockIdx.x >> 3);
  const int mt = L / nTiles;
  const int nt = L - mt * nTiles;
  const long mBase = (long)mt << 7;
  const int  nBase = nt << 7;

  // staging: LDS dest is wave-uniform base + lane*16B. Lane (row=sRow,
  // slot=lane&3) fetches global chunk gCol so storage is XOR-swizzled.
  const int sRow   = (wave << 4) + (lane >> 2);        // 0..63
  const int sCol   = (lane & 3) << 3;                  // LDS slot (halves)
  const int gCol   = ((lane & 3) ^ ((sRow >> 1) & 3)) << 3;  // global chunk

  const _Float16* aG0 = A + (mBase + sRow) * lda + gCol;
  const _Float16* aG1 = A + (mBase + sRow + 64) * lda + gCol;   // same swz (64 ≡ 0 mod 4 after >>1)
  const _Float16* bG0 = Bt + (long)(nBase + sRow) * K + gCol;
  const _Float16* bG1 = Bt + (long)(nBase + sRow + 64) * K + gCol;
  const int offS0 = sRow * 32 + sCol;
  const int offS1 = offS0 + 64 * 32;

  // fragment-read swizzle: row = (wr<<6)+(i<<4)+l16 -> swz = (l16>>1)&3
  const int fswz = ((l16 >> 1) & 3) << 3;

  floatx4 acc[4][4] = {};

  const int nK = K >> 5;
  // prologue: stage k=0 into buf 0
  gload16(aG0, &sA[0][offS0]);
  gload16(aG1, &sA[0][offS1]);
  gload16(bG0, &sB[0][offS0]);
  gload16(bG1, &sB[0][offS1]);

  for (int kk = 0; kk < nK; kk++) {
    const int cur = kk & 1;
    __syncthreads();  // drains vmcnt(0): buf[cur] ready; orders vs prev reads of buf[cur^1]
    if (kk + 1 < nK) {
      const int ko = (kk + 1) << 5;
      gload16(aG0 + ko, &sA[cur ^ 1][offS0]);
      gload16(aG1 + ko, &sA[cur ^ 1][offS1]);
      gload16(bG0 + ko, &sB[cur ^ 1][offS0]);
      gload16(bG1 + ko, &sB[cur ^ 1][offS1]);
    }
    half8 aF[4], bF[4];
#pragma unroll
    for (int i = 0; i < 4; i++)
      aF[i] = *(const half8*)(&sA[cur][((wr << 6) + (i << 4) + l16) * 32 + ((quad << 3) ^ fswz)]);
#pragma unroll
    for (int j = 0; j < 4; j++)
      bF[j] = *(const half8*)(&sB[cur][((wc << 6) + (j << 4) + l16) * 32 + ((quad << 3) ^ fswz)]);
#pragma unroll
    for (int i = 0; i < 4; i++)
#pragma unroll
      for (int j = 0; j < 4; j++)
        acc[i][j] = __builtin_amdgcn_mfma_f32_16x16x32_f16(aF[i], bF[j], acc[i][j], 0, 0, 0);
  }

  if constexpr (EPI < 2) {
#pragma unroll
    for (int j = 0; j < 4; j++) {
      int col = nBase + (wc << 6) + (j << 4) + l16;
      float bv = bias[col];
#pragma unroll
      for (int i = 0; i < 4; i++) {
        long row = mBase + (wr << 6) + (i << 4) + (quad << 2);
#pragma unroll
        for (int r = 0; r < 4; r++) {
          float v = acc[i][j][r] + bv;
          if (EPI == 1) v = fmaxf(v, 0.0f);
          C[(size_t)(row + r) * N + col] = (_Float16)v;
        }
      }
    }
  } else {
    // fused relu + ragged-mean pooling. 1024 rows/batch = 8 tiles: whole
    // block is one batch. C/D layout: col = lane&15, row = quad*4 + reg.
    int b = mt >> 3;
    int validw = lengths[b] - (NGRAM - 1);
    float inv = 1.0f / (float)validw;
    int wBase = ((mt & 7) << 7) + (wr << 6);
#pragma unroll
    for (int j = 0; j < 4; j++) {
      int col = (wc << 6) + (j << 4) + l16;
      float bv = bias[col];
      float p = 0.0f;
#pragma unroll
      for (int i = 0; i < 4; i++) {
#pragma unroll
        for (int r = 0; r < 4; r++) {
          int w = wBase + (i << 4) + (quad << 2) + r;
          float v = fmaxf(acc[i][j][r] + bv, 0.0f);
          p += (w < validw) ? v : 0.0f;
        }
      }
      p *= inv;
      p += __shfl_xor(p, 16, 64);
      p += __shfl_xor(p, 32, 64);
      if (quad == 0) red[wr][col] = p;
    }
    __syncthreads();
    if (tid < 128) atomicAdd(out + b * H2D + tid, red[0][tid] + red[1][tid]);
  }
}

// ---------------------------------------------------------------- launcher
extern "C" void kernel_launch(void* const* d_in, const int* in_sizes, int n_in,
                              void* d_out, int out_size, void* d_ws, size_t ws_size,
                              hipStream_t stream) {
  const int*   x       = (const int*)d_in[0];
  const int*   lengths = (const int*)d_in[1];
  const float* table   = (const float*)d_in[2];
  const float* W_slide = (const float*)d_in[3];
  const float* b_slide = (const float*)d_in[4];
  const float* W1      = (const float*)d_in[5];
  const float* b1      = (const float*)d_in[6];
  const float* W2      = (const float*)d_in[7];
  const float* b2      = (const float*)d_in[8];
  float* out = (float*)d_out;

  // workspace layout (halves). emb gets +4096 pad: padded windows read past
  // the logical end (finite poison * zero pad-weights, rows masked in pooling).
  _Float16* ws  = (_Float16*)d_ws;
  _Float16* emb = ws;                                   // 64*1024*304
  _Float16* WsT = emb + (size_t)MTOT * EMB_P + 4096;    // 512*1536
  _Float16* W1T = WsT + (size_t)H0 * K1P;               // 256*512
  _Float16* W2T = W1T + (size_t)H1D * H0;               // 128*256
  _Float16* h1  = W2T + (size_t)H2D * H1D;              // 65536*512
  _Float16* h2  = h1 + (size_t)MTOT * H0;               // 65536*256

  gather_kernel<<<(MTOT * (EMB_P / 4)) / 256, 256, 0, stream>>>(x, table, emb, out);
  {
    int total = H0 * K1P + H1D * H0 + H2D * H1D;
    wprep_kernel<<<(total + 255) / 256, 256, 0, stream>>>(W_slide, W1, W2, WsT, W1T, W2T);
  }
  // L1: win @ W_slide + b_slide (no relu) -> h1 fp16
  gemm_nt<0><<<(MTOT / 128) * (H0 / 128), 256, 0, stream>>>(
      emb, WsT, b_slide, h1, nullptr, nullptr, H0, K1P, EMB_P, H0 / 128);
  // L2: relu(h1 @ W1 + b1) -> h2 fp16
  gemm_nt<1><<<(MTOT / 128) * (H1D / 128), 256, 0, stream>>>(
      h1, W1T, b1, h2, nullptr, nullptr, H1D, H0, H0, H1D / 128);
  // L3: relu(h2 @ W2 + b2), fused masked-mean pooling -> out
  gemm_nt<2><<<(MTOT / 128) * (H2D / 128), 256, 0, stream>>>(
      h2, W2T, b2, nullptr, out, lengths, H2D, H1D, H1D, H2D / 128);
}

// Round 4
// 364.648 us; speedup vs baseline: 1.0952x; 1.0036x over previous
//
#include <hip/hip_runtime.h>

// Problem constants
#define B_N    64
#define S_LEN  1024
#define EMB    300
#define EMB_P  304              // padded token stride (halves) -> 608B, 16B-aligned
#define NGRAM  5
#define WPAD   1024             // windows per batch padded 1020 -> 1024
#define MTOT   (B_N * WPAD)     // 65536 rows
#define K1P    1536             // padded K for layer 1 (5*304 = 1520 -> 1536)
#define H0     512
#define H1D    256
#define H2D    128

#define GATHER_BLOCKS ((MTOT * (EMB_P / 4)) / 256)   // 19456
#define WPREP_THREADS (H0 * K1P + H1D * H0 + H2D * H1D)
#define WPREP_BLOCKS  ((WPREP_THREADS + 255) / 256)  // 3712

typedef _Float16 half8 __attribute__((ext_vector_type(8)));
typedef float  floatx4 __attribute__((ext_vector_type(4)));

typedef const __attribute__((address_space(1))) void* gptr_t;
typedef __attribute__((address_space(3))) void* sptr_t;

__device__ __forceinline__ void gload16(const void* g, void* s) {
  __builtin_amdgcn_global_load_lds((gptr_t)g, (sptr_t)s, 16, 0, 0);
}

// wait own 4 newest loads may remain outstanding, then workgroup barrier.
// Raw s_barrier (no implicit vmcnt(0) drain) -- keeps next step's 4
// global_load_lds in flight across the barrier (prefetch distance 2).
__device__ __forceinline__ void pipe_barrier() {
  __asm__ volatile("s_waitcnt vmcnt(4)\n\ts_barrier" ::: "memory");
}

// ------------- fused prep: gather table[x]->fp16, weight transpose, zero out
__global__ void prep_kernel(const int* __restrict__ x,
                            const float* __restrict__ table,
                            _Float16* __restrict__ emb,
                            float* __restrict__ out,
                            const float* __restrict__ Ws,
                            const float* __restrict__ W1,
                            const float* __restrict__ W2,
                            _Float16* __restrict__ WsT,
                            _Float16* __restrict__ W1T,
                            _Float16* __restrict__ W2T) {
  const int bid = blockIdx.x;
  if (bid < GATHER_BLOCKS) {
    if (bid < 32) out[bid * 256 + threadIdx.x] = 0.0f;  // zero 8192 outputs
    const int CH = EMB_P / 4;  // 76
    int tid = bid * 256 + threadIdx.x;
    int tok = tid / CH;
    int c   = tid - tok * CH;
    int e   = c << 2;
    _Float16 h0, h1, h2, h3;
    if (e < EMB) {
      float4 v = *(const float4*)(table + (size_t)x[tok] * EMB + e);
      h0 = (_Float16)v.x; h1 = (_Float16)v.y; h2 = (_Float16)v.z; h3 = (_Float16)v.w;
    } else {
      h0 = h1 = h2 = h3 = (_Float16)0.0f;
    }
    union { float2 f2; _Float16 h[4]; } u;
    u.h[0] = h0; u.h[1] = h1; u.h[2] = h2; u.h[3] = h3;
    *(float2*)(emb + (size_t)tok * EMB_P + e) = u.f2;
  } else {
    int tid = (bid - GATHER_BLOCKS) * 256 + threadIdx.x;
    const int NS = H0 * K1P;
    const int N1 = H1D * H0;
    const int N2 = H2D * H1D;
    if (tid < NS) {
      int n = tid / K1P, k = tid - n * K1P;
      float v = 0.0f;
      if (k < NGRAM * EMB_P) {
        int tn = k / EMB_P, e = k - tn * EMB_P;
        if (e < EMB) v = Ws[(size_t)(tn * EMB + e) * H0 + n];
      }
      WsT[tid] = (_Float16)v;
    } else if (tid < NS + N1) {
      int t = tid - NS;
      int n = t / H0, k = t - n * H0;
      W1T[t] = (_Float16)W1[(size_t)k * H1D + n];
    } else if (tid < NS + N1 + N2) {
      int t = tid - (NS + N1);
      int n = t / H1D, k = t - n * H1D;
      W2T[t] = (_Float16)W2[(size_t)k * H2D + n];
    }
  }
}

// ------------------------------------------------------------ NT MFMA GEMM
// C[M,N] = A[M,K] @ Bt[N,K]^T, 128x128 tile, BK=32, 4 waves (2x2), fp16 MFMA.
// 3-stage LDS pipeline (prefetch distance 2) with raw s_barrier + vmcnt(4):
// next step's loads stay in flight across the barrier. XOR-swizzled 16B
// chunks (0 bank conflicts). XCD-affine block swizzle for A-tile L2 reuse.
// EPI 0: +bias, store fp16.  EPI 1: +bias, relu, store fp16.
// EPI 2: +bias, relu, masked-mean pooling via atomics (N=128, one tile).
template <int EPI>
__global__ __launch_bounds__(256, 3)
void gemm_nt(const _Float16* __restrict__ A, const _Float16* __restrict__ Bt,
             const float* __restrict__ bias, _Float16* __restrict__ C,
             float* __restrict__ out, const int* __restrict__ lengths,
             int N, int K, int lda, int nTiles) {
  __shared__ _Float16 sA[3][128 * 32];
  __shared__ _Float16 sB[3][128 * 32];
  __shared__ float red[2][128];

  const int tid  = threadIdx.x;
  const int wave = tid >> 6;
  const int lane = tid & 63;
  const int wr   = wave >> 1, wc = wave & 1;
  const int quad = lane >> 4, l16 = lane & 15;

  // XCD-affine remap: xcd = blockIdx&7 gets a contiguous logical range;
  // nt varies fastest within it -> A-tile L2 reuse within one XCD.
  const int perX = gridDim.x >> 3;
  const int L    = (blockIdx.x & 7) * perX + (blockIdx.x >> 3);
  const int mt = L / nTiles;
  const int nt = L - mt * nTiles;
  const long mBase = (long)mt << 7;
  const int  nBase = nt << 7;

  // staging: LDS dest is wave-uniform base + lane*16B. Lane (row=sRow,
  // slot=lane&3) fetches global chunk gCol so storage is XOR-swizzled.
  const int sRow   = (wave << 4) + (lane >> 2);        // 0..63
  const int sCol   = (lane & 3) << 3;                  // LDS slot (halves)
  const int gCol   = ((lane & 3) ^ ((sRow >> 1) & 3)) << 3;  // global chunk

  const _Float16* aG0 = A + (mBase + sRow) * lda + gCol;
  const _Float16* aG1 = A + (mBase + sRow + 64) * lda + gCol;
  const _Float16* bG0 = Bt + (long)(nBase + sRow) * K + gCol;
  const _Float16* bG1 = Bt + (long)(nBase + sRow + 64) * K + gCol;
  const int offS0 = sRow * 32 + sCol;
  const int offS1 = offS0 + 64 * 32;

  // fragment-read swizzle: row = (wr<<6)+(i<<4)+l16 -> swz = (l16>>1)&3
  const int fswz = ((l16 >> 1) & 3) << 3;

  floatx4 acc[4][4] = {};

  const int nK = K >> 5;
  // prologue: stage steps 0,1 into bufs 0,1 (8 loads outstanding)
  gload16(aG0, &sA[0][offS0]);
  gload16(aG1, &sA[0][offS1]);
  gload16(bG0, &sB[0][offS0]);
  gload16(bG1, &sB[0][offS1]);
  gload16(aG0 + 32, &sA[1][offS0]);
  gload16(aG1 + 32, &sA[1][offS1]);
  gload16(bG0 + 32, &sB[1][offS0]);
  gload16(bG1 + 32, &sB[1][offS1]);

  int cur = 0;
  for (int kk = 0; kk < nK; kk++) {
    // own step-k loads done (<=4 newest outstanding), then barrier: all
    // waves' step-k loads landed; step-k+1 loads remain in flight.
    pipe_barrier();
    if (kk + 2 < nK) {
      const int nxt = cur >= 1 ? cur - 1 : 2;  // (kk+2)%3
      const int ko = (kk + 2) << 5;
      gload16(aG0 + ko, &sA[nxt][offS0]);
      gload16(aG1 + ko, &sA[nxt][offS1]);
      gload16(bG0 + ko, &sB[nxt][offS0]);
      gload16(bG1 + ko, &sB[nxt][offS1]);
    }
    half8 aF[4], bF[4];
#pragma unroll
    for (int i = 0; i < 4; i++)
      aF[i] = *(const half8*)(&sA[cur][((wr << 6) + (i << 4) + l16) * 32 + ((quad << 3) ^ fswz)]);
#pragma unroll
    for (int j = 0; j < 4; j++)
      bF[j] = *(const half8*)(&sB[cur][((wc << 6) + (j << 4) + l16) * 32 + ((quad << 3) ^ fswz)]);
#pragma unroll
    for (int i = 0; i < 4; i++)
#pragma unroll
      for (int j = 0; j < 4; j++)
        acc[i][j] = __builtin_amdgcn_mfma_f32_16x16x32_f16(aF[i], bF[j], acc[i][j], 0, 0, 0);
    cur = cur < 2 ? cur + 1 : 0;
  }

  if constexpr (EPI < 2) {
#pragma unroll
    for (int j = 0; j < 4; j++) {
      int col = nBase + (wc << 6) + (j << 4) + l16;
      float bv = bias[col];
#pragma unroll
      for (int i = 0; i < 4; i++) {
        long row = mBase + (wr << 6) + (i << 4) + (quad << 2);
#pragma unroll
        for (int r = 0; r < 4; r++) {
          float v = acc[i][j][r] + bv;
          if (EPI == 1) v = fmaxf(v, 0.0f);
          C[(size_t)(row + r) * N + col] = (_Float16)v;
        }
      }
    }
  } else {
    // fused relu + ragged-mean pooling. 1024 rows/batch = 8 tiles: whole
    // block is one batch. C/D layout: col = lane&15, row = quad*4 + reg.
    int b = mt >> 3;
    int validw = lengths[b] - (NGRAM - 1);
    float inv = 1.0f / (float)validw;
    int wBase = ((mt & 7) << 7) + (wr << 6);
#pragma unroll
    for (int j = 0; j < 4; j++) {
      int col = (wc << 6) + (j << 4) + l16;
      float bv = bias[col];
      float p = 0.0f;
#pragma unroll
      for (int i = 0; i < 4; i++) {
#pragma unroll
        for (int r = 0; r < 4; r++) {
          int w = wBase + (i << 4) + (quad << 2) + r;
          float v = fmaxf(acc[i][j][r] + bv, 0.0f);
          p += (w < validw) ? v : 0.0f;
        }
      }
      p *= inv;
      p += __shfl_xor(p, 16, 64);
      p += __shfl_xor(p, 32, 64);
      if (quad == 0) red[wr][col] = p;
    }
    __syncthreads();
    if (tid < 128) atomicAdd(out + b * H2D + tid, red[0][tid] + red[1][tid]);
  }
}

// ---------------------------------------------------------------- launcher
extern "C" void kernel_launch(void* const* d_in, const int* in_sizes, int n_in,
                              void* d_out, int out_size, void* d_ws, size_t ws_size,
                              hipStream_t stream) {
  const int*   x       = (const int*)d_in[0];
  const int*   lengths = (const int*)d_in[1];
  const float* table   = (const float*)d_in[2];
  const float* W_slide = (const float*)d_in[3];
  const float* b_slide = (const float*)d_in[4];
  const float* W1      = (const float*)d_in[5];
  const float* b1      = (const float*)d_in[6];
  const float* W2      = (const float*)d_in[7];
  const float* b2      = (const float*)d_in[8];
  float* out = (float*)d_out;

  // workspace layout (halves). emb gets +4096 pad: padded windows read past
  // the logical end (finite poison * zero pad-weights, rows masked in pooling).
  _Float16* ws  = (_Float16*)d_ws;
  _Float16* emb = ws;                                   // 64*1024*304
  _Float16* WsT = emb + (size_t)MTOT * EMB_P + 4096;    // 512*1536
  _Float16* W1T = WsT + (size_t)H0 * K1P;               // 256*512
  _Float16* W2T = W1T + (size_t)H1D * H0;               // 128*256
  _Float16* h1  = W2T + (size_t)H2D * H1D;              // 65536*512
  _Float16* h2  = h1 + (size_t)MTOT * H0;               // 65536*256

  prep_kernel<<<GATHER_BLOCKS + WPREP_BLOCKS, 256, 0, stream>>>(
      x, table, emb, out, W_slide, W1, W2, WsT, W1T, W2T);
  // L1: win @ W_slide + b_slide (no relu) -> h1 fp16
  gemm_nt<0><<<(MTOT / 128) * (H0 / 128), 256, 0, stream>>>(
      emb, WsT, b_slide, h1, nullptr, nullptr, H0, K1P, EMB_P, H0 / 128);
  // L2: relu(h1 @ W1 + b1) -> h2 fp16
  gemm_nt<1><<<(MTOT / 128) * (H1D / 128), 256, 0, stream>>>(
      h1, W1T, b1, h2, nullptr, nullptr, H1D, H0, H0, H1D / 128);
  // L3: relu(h2 @ W2 + b2), fused masked-mean pooling -> out
  gemm_nt<2><<<(MTOT / 128) * (H2D / 128), 256, 0, stream>>>(
      h2, W2T, b2, nullptr, out, lengths, H2D, H1D, H1D, H2D / 128);
}